// Round 8
// baseline (95.256 us; speedup 1.0000x reference)
//
#include <hip/hip_runtime.h>
#include <math.h>

#define BB 8
#define HWH (512*512)
#define NID 15
#define NSEG (BB*NID)
#define NBINS 256
#define AAF ((float)NBINS/13.0f)
#define LOG2E 1.442695041f
#define LN2 0.6931471806f

typedef unsigned int uint32;
typedef unsigned long long uint64;

__device__ __forceinline__ float ftanh(float x){
    float t = __expf(2.0f*x);
    return 1.0f - 2.0f*__builtin_amdgcn_rcpf(t + 1.0f);
}
__device__ __forceinline__ float fsigmoid(float x){
    return __builtin_amdgcn_rcpf(1.0f + __expf(-x));
}

// ---- phase1f: per-chunk id-stats (packed u64 + sigma + sigma^2) + focal/bgseed ----
__global__ __launch_bounds__(256, 8) void phase1f(const float* __restrict__ pred,
        const int* __restrict__ labels, const int* __restrict__ inst,
        uint64* __restrict__ pstat64, float* __restrict__ pstatf,
        float* __restrict__ pstatf2,
        float* __restrict__ bgseed_p, float* __restrict__ focal_p){
    int blk = blockIdx.x;            // 2048 blocks, 256 per image
    int b = blk >> 8;
    int t = threadIdx.x;
    int q = (blk & 255)*256 + t;     // float4 index in image

    __shared__ uint64 s64[NID];
    __shared__ float ssig[NID], ssig2[NID];
    __shared__ float wfb[4][2];
    if (t < NID){ s64[t] = 0ull; ssig[t] = 0.0f; ssig2[t] = 0.0f; }
    __syncthreads();

    const int Q = HWH/4;
    const float4* P = (const float4*)(pred + (size_t)b*6*HWH);
    const int4* L = (const int4*)(labels + (size_t)b*3*HWH);
    const int4* I = (const int4*)(inst + (size_t)b*HWH);
    float4 sg4 = P[2*Q+q], z3 = P[3*Q+q], z4 = P[4*Q+q], z5 = P[5*Q+q];
    int4 id4 = I[q];
    int4 l0 = L[q], l1 = L[Q+q], l2 = L[2*Q+q];
    int p = q*4;
    int w0 = p & 511, h0 = p >> 9;

    float facc = 0.0f, bacc = 0.0f;
    auto px = [&](float sgv, float z3v, float z4v, float z5v, int id,
                  int L0, int L1, int L2, int wv){
        float seed = fsigmoid(z5v);
        if (L2 == 0) bacc += seed*seed;
        int tc = 0, best = L0;
        if (L1 > best){ tc = 1; best = L1; }
        if (L2 > best){ tc = 2; }
        float m = fmaxf(z3v, fmaxf(z4v, z5v));
        float e3 = __expf(z3v-m), e4 = __expf(z4v-m), e5 = __expf(z5v-m);
        float sum = e3+e4+e5;
        float lse = m + __logf(sum);
        float zt = (tc==0) ? z3v : ((tc==1) ? z4v : z5v);
        float et = (tc==0) ? e3  : ((tc==1) ? e4  : e5);
        float lp = zt - lse;
        float pt = et*__builtin_amdgcn_rcpf(sum);
        float om = 1.0f - pt;
        facc -= om*om*lp;
        if (id > 0){
            atomicAdd(&s64[id-1],
                      (1ull<<42) | ((uint64)(uint32)wv<<21) | (uint64)(uint32)h0);
            atomicAdd(&ssig[id-1], sgv);
            atomicAdd(&ssig2[id-1], sgv*sgv);
        }
    };
    px(sg4.x, z3.x, z4.x, z5.x, id4.x, l0.x, l1.x, l2.x, w0);
    px(sg4.y, z3.y, z4.y, z5.y, id4.y, l0.y, l1.y, l2.y, w0+1);
    px(sg4.z, z3.z, z4.z, z5.z, id4.z, l0.z, l1.z, l2.z, w0+2);
    px(sg4.w, z3.w, z4.w, z5.w, id4.w, l0.w, l1.w, l2.w, w0+3);

    for (int o = 32; o; o >>= 1){
        facc += __shfl_xor(facc, o);
        bacc += __shfl_xor(bacc, o);
    }
    if ((t & 63) == 0){ wfb[t>>6][0] = facc; wfb[t>>6][1] = bacc; }
    __syncthreads();
    if (t < NID){
        pstat64[blk*16 + t] = s64[t];
        pstatf [blk*16 + t] = ssig[t];
        pstatf2[blk*16 + t] = ssig2[t];
    }
    if (t == 0){
        focal_p[blk]  = wfb[0][0]+wfb[1][0]+wfb[2][0]+wfb[3][0];
        bgseed_p[blk] = wfb[0][1]+wfb[1][1]+wfb[2][1]+wfb[3][1];
    }
}

// ---- phaseR: reduce partials -> stats(cnt), derived, var_sum, focalR, bgseedR ----
__global__ __launch_bounds__(512) void phaseR(const uint64* __restrict__ pstat64,
        const float* __restrict__ pstatf, const float* __restrict__ pstatf2,
        const float* __restrict__ focal_p, const float* __restrict__ bgseed_p,
        float* __restrict__ stats, float* __restrict__ derived,
        float* __restrict__ results,
        float* __restrict__ focalR, float* __restrict__ bgseedR){
    int b = blockIdx.x;              // 8 blocks
    int t = threadIdx.x;
    int k = t & 15, chunk = t >> 4;  // 32 chunks x 8 partial-blocks
    float acnt = 0, asw = 0, ash = 0, af = 0, af2 = 0;
    for (int i = 0; i < 8; i++){
        int blk = b*256 + chunk*8 + i;
        uint64 v = pstat64[blk*16 + k];
        acnt += (float)(uint32)(v >> 42);
        asw  += (float)(uint32)((v >> 21) & 0x1FFFFF);
        ash  += (float)(uint32)(v & 0x1FFFFF);
        af   += pstatf[blk*16 + k];
        af2  += pstatf2[blk*16 + k];
    }
    __shared__ float tc[16], tw[16], th[16], ts[16], ts2[16];
    if (t < 16){ tc[t]=0; tw[t]=0; th[t]=0; ts[t]=0; ts2[t]=0; }
    __syncthreads();
    atomicAdd(&tc[k], acnt);
    atomicAdd(&tw[k], asw);
    atomicAdd(&th[k], ash);
    atomicAdd(&ts[k], af);
    atomicAdd(&ts2[k], af2);
    __syncthreads();
    if (t < NID){
        float cnt = tc[t];
        float safe = fmaxf(cnt, 1.0f);
        float inv = 1.0f/safe;
        const float SC = 2.0f/511.0f;
        derived[(b*NID+t)*4+0] = tw[t]*SC*inv;
        derived[(b*NID+t)*4+1] = th[t]*SC*inv;
        float sm = ts[t]*inv;
        derived[(b*NID+t)*4+2] = __expf(10.0f*sm);
        derived[(b*NID+t)*4+3] = sm;
        stats[b*60 + t*4] = cnt;
        // var_sum = sum((sigma - sm)^2) = sum(sigma^2) - cnt*sm^2
        results[(size_t)(b*NID+t)*3 + 1] = ts2[t] - cnt*sm*sm;
    }
    int w = t >> 6, lane = t & 63;
    if (w == 0){
        float f = 0;
        for (int j = 0; j < 4; j++) f += focal_p[b*256 + j*64 + lane];
        for (int o = 32; o; o >>= 1) f += __shfl_xor(f, o);
        if (lane == 0) focalR[b] = f;
    } else if (w == 1){
        float g = 0;
        for (int j = 0; j < 4; j++) g += bgseed_p[b*256 + j*64 + lane];
        for (int o = 32; o; o >>= 1) g += __shfl_xor(g, o);
        if (lane == 0) bgseedR[b] = g;
    }
}

// ---- phaseLH: one block = one pixel-slice, ALL 15 ids, 256-bin LDS histograms ----
__global__ __launch_bounds__(512, 8) void phaseLH(const float* __restrict__ pred,
        const int* __restrict__ inst, const float* __restrict__ derived,
        uint32* __restrict__ part, float* __restrict__ part2, int S){
    int idx = blockIdx.x;
    int b = idx & 7;                 // XCD affinity
    int sp = idx >> 3;
    int t = threadIdx.x;

    __shared__ __align__(16) uint32 hist[NID*NBINS];   // (count<<16)|fg, 15 KB
    __shared__ float scx[NID], scy[NID], ssl[NID], sCs[NID];
    __shared__ float vsB[NID];
    {
        uint4* hz = (uint4*)hist;
        for (int i = t; i < NID*NBINS/4; i += 512) hz[i] = make_uint4(0,0,0,0);
    }
    if (t < NID){
        const float* d0 = derived + (size_t)(b*NID + t)*4;
        scx[t] = d0[0]; scy[t] = d0[1]; ssl[t] = d0[2];
        sCs[t] = LOG2E*AAF*d0[2];
        vsB[t] = 0.0f;
    }
    __syncthreads();

    const int Q = HWH/4;
    int qps = Q / S;
    int q0 = sp * qps;
    const float* pb = pred + (size_t)b*6*HWH;
    const float4* P0 = (const float4*)pb;
    const float4* P1 = P0 + Q;
    const float4* P5 = P0 + 5*Q;
    const int4* I = (const int4*)(inst + (size_t)b*HWH);
    const float SC = 2.0f/511.0f;

    for (int q = q0 + t; q < q0 + qps; q += 512){
        int4 id4 = I[q];
        float4 a = P0[q], c = P1[q], z54 = P5[q];
        int p = q*4;
        float gx = (float)(p & 511)*SC;
        float gy = (float)(p >> 9)*SC;
        auto px = [&](float av, float cv, float z5v, int id, float gxv){
            float ex = ftanh(av) + gxv;
            float ey = ftanh(cv) + gy;
            int own = id - 1;
            float r2own = 0.0f;
            #pragma unroll
            for (int j = 0; j < NID; j++){
                float dx = ex - scx[j], dy = ey - scy[j];
                float r2 = fmaf(dx, dx, dy*dy);
                if (j == own) r2own = r2;            // cndmask, no branch
                float binf = fmaf(-sCs[j], r2, (float)NBINS);
                binf = fminf(fmaxf(binf, 0.0f), (float)(NBINS-1));
                atomicAdd(&hist[j*NBINS + (int)binf], 65536u);
            }
            if (own >= 0){
                float d = __expf(-ssl[own]*r2own);
                float e = fmaf(-2.0f, d, 2.0f);
                float bf = fmaf(__log2f(e), AAF, (float)NBINS - AAF);
                bf = fminf(fmaxf(bf, 0.0f), (float)(NBINS-1));
                float bb = fmaf(-sCs[own], r2own, (float)NBINS);
                bb = fminf(fmaxf(bb, 0.0f), (float)(NBINS-1));
                atomicAdd(&hist[own*NBINS + (int)bb], 0xFFFF0000u); // undo bg
                atomicAdd(&hist[own*NBINS + (int)bf], 65537u);      // fg entry
                float seed = fsigmoid(z5v);
                float sd = seed - d;
                atomicAdd(&vsB[own], sd*sd);
            }
        };
        px(a.x, c.x, z54.x, id4.x, gx);
        px(a.y, c.y, z54.y, id4.y, gx+SC);
        px(a.z, c.z, z54.z, id4.z, gx+2*SC);
        px(a.w, c.w, z54.w, id4.w, gx+3*SC);
    }
    __syncthreads();
    uint4* dst = (uint4*)(part + (size_t)(b*S + sp)*NID*NBINS);
    const uint4* hs = (const uint4*)hist;
    for (int i = t; i < NID*NBINS/4; i += 512) dst[i] = hs[i];
    if (t < NID) part2[(size_t)(b*S + sp)*NID + t] = vsB[t];
}

// ---- phaseM: merge S/8 slices -> 8 group-histograms per segment ----
__global__ __launch_bounds__(256) void phaseM(const uint32* __restrict__ part,
        uint32* __restrict__ part_m, int S){
    int idx = blockIdx.x;            // 960 = 8 img x 15 id x 8 groups
    int b = idx & 7;
    int r = idx >> 3;                // 0..119
    int k = r % NID;
    int g = r / NID;                 // 0..7
    int t = threadIdx.x;             // = bin
    int spn = S >> 3;
    uint32 acc = 0;
    for (int i = 0; i < spn; i++){
        const uint32* src = part + ((size_t)(b*S + g*spn + i)*NID + k)*NBINS;
        acc += src[t];
    }
    part_m[((size_t)(b*8 + g)*NID + k)*NBINS + t] = acc;
}

// ---- phaseLS: merge 8 groups + descending Lovasz scan ----
__global__ __launch_bounds__(256) void phaseLS(const uint32* __restrict__ part_m,
        const float* __restrict__ part2, const float* __restrict__ stats,
        float* __restrict__ results, int S){
    int idx = blockIdx.x;            // 120
    int b = idx & 7, k = idx >> 3;
    int seg = b*NID + k;
    int t = threadIdx.x;             // 256

    __shared__ uint32 hc[NBINS], hg[NBINS];
    __shared__ uint32 wbc[4], wbg[4], wexc[4], wexg[4];
    __shared__ float wsum[4];

    uint32 c = 0, g = 0;
    for (int gi = 0; gi < 8; gi++){
        uint32 v = part_m[((size_t)(b*8 + gi)*NID + k)*NBINS + t];
        c += v >> 16; g += v & 0xFFFFu;
    }
    hc[t] = c; hg[t] = g;
    __syncthreads();

    // thread t handles bin NBINS-1-t (descending)
    uint32 cd = hc[NBINS-1-t], gd = hg[NBINS-1-t];
    uint32 ci = cd, gi2 = gd;
    int lane = t & 63, w = t >> 6;
    for (int o = 1; o < 64; o <<= 1){
        uint32 cu = __shfl_up(ci, o);
        uint32 gu = __shfl_up(gi2, o);
        if (lane >= o){ ci += cu; gi2 += gu; }
    }
    if (lane == 63){ wbc[w] = ci; wbg[w] = gi2; }
    __syncthreads();
    if (t == 0){
        uint32 rc = 0, rg = 0;
        for (int i = 0; i < 4; i++){
            uint32 a = wbc[i], bq = wbg[i];
            wexc[i] = rc; wexg[i] = rg;
            rc += a; rg += bq;
        }
    }
    __syncthreads();

    float G = stats[b*60 + k*4];
    float contrib = 0.0f;
    if (G > 0.0f && (cd | gd)){
        uint32 nb = wexc[w] + (ci - cd);     // count before this bin
        uint32 gb = wexg[w] + (gi2 - gd);
        float jp = 0.0f;
        if (nb > 0) jp = 1.0f - (G - (float)gb)/(G + (float)(nb - gb));
        uint32 n = nb + cd, gg = gb + gd;
        float j2 = 1.0f - (G - (float)gg)/(G + (float)(n - gg));
        int bin = NBINS-1-t;
        float ev = __expf(LN2*(((float)bin + 0.5f)*(13.0f/(float)NBINS) - 12.0f));
        contrib = ev*(j2 - jp);
    }
    for (int o = 32; o; o >>= 1) contrib += __shfl_xor(contrib, o);
    if ((t & 63) == 0) wsum[w] = contrib;
    __syncthreads();
    if (t == 0)
        results[(size_t)seg*3 + 0] = wsum[0]+wsum[1]+wsum[2]+wsum[3];
    if (w == 1){
        float ss = 0.0f;
        for (int sp = lane; sp < S; sp += 64)
            ss += part2[(size_t)(b*S + sp)*NID + k];
        for (int o = 32; o; o >>= 1) ss += __shfl_xor(ss, o);
        if (lane == 0) results[(size_t)seg*3 + 2] = ss;
    }
}

// ---------------- phase5: final combine ----------------
__global__ void phase5(const float* __restrict__ stats, const float* __restrict__ results,
                       const float* __restrict__ bgseedR, const float* __restrict__ focalR,
                       float* __restrict__ out){
    int t = threadIdx.x;
    __shared__ float per_b[BB];
    if (t < BB){
        float nvalid = 0.0f, lsum = 0.0f, vsum = 0.0f, ssum = 0.0f;
        for (int k = 0; k < NID; k++){
            int seg = t*NID + k;
            float cnt = stats[t*60 + k*4];
            if (cnt > 0.0f){
                nvalid += 1.0f;
                lsum += results[seg*3+0];
                vsum += results[seg*3+1]/cnt;
                ssum += results[seg*3+2];
            }
        }
        float nobj = fmaxf(nvalid, 1.0f);
        per_b[t] = lsum/nobj + 10.0f*(vsum/nobj) + (bgseedR[t] + ssum)/(float)HWH;
    }
    __syncthreads();
    if (t == 0){
        float s = 0.0f, fs = 0.0f;
        for (int b = 0; b < BB; b++){ s += per_b[b]; fs += focalR[b]; }
        out[0] = s/(float)BB + fs/(float)(BB*HWH);
    }
}

extern "C" void kernel_launch(void* const* d_in, const int* in_sizes, int n_in,
                              void* d_out, int out_size, void* d_ws, size_t ws_size,
                              hipStream_t stream){
    const float* pred  = (const float*)d_in[0];
    const int*   labels= (const int*)d_in[1];
    const int*   inst  = (const int*)d_in[2];
    float* out = (float*)d_out;

    auto need = [](int S){
        return (size_t)BB*S*NID*NBINS*4ull       // hist slabs
             + (size_t)120*8*NBINS*4ull          // group merge slabs
             + (size_t)BB*S*NID*4ull             // seed partials
             + 2048ull*16*8 + 2048ull*16*4*2     // pstat64 + pstatf + pstatf2
             + 2048ull*4*2                       // focal_p, bgseed_p
             + (480+480+360+16)*4ull;
    };
    int S = 16;
    if      (ws_size >= need(128)) S = 128;
    else if (ws_size >= need(64))  S = 64;
    else if (ws_size >= need(32))  S = 32;

    uint32* part   = (uint32*)d_ws;
    uint32* part_m = part + (size_t)BB*S*NID*NBINS;
    float* part2   = (float*)(part_m + (size_t)120*8*NBINS);
    uint64* pstat64= (uint64*)(part2 + (size_t)BB*S*NID);
    float* pstatf  = (float*)(pstat64 + 2048*16);
    float* pstatf2 = pstatf + 2048*16;
    float* focal_p = pstatf2 + 2048*16;
    float* bgseed_p= focal_p + 2048;
    float* stats   = bgseed_p + 2048;
    float* derived = stats + 480;
    float* results = derived + 480;
    float* focalR  = results + 360;
    float* bgseedR = focalR + 8;

    hipLaunchKernelGGL(phase1f, dim3(2048), dim3(256), 0, stream,
                       pred, labels, inst, pstat64, pstatf, pstatf2, bgseed_p, focal_p);
    hipLaunchKernelGGL(phaseR, dim3(8), dim3(512), 0, stream,
                       pstat64, pstatf, pstatf2, focal_p, bgseed_p,
                       stats, derived, results, focalR, bgseedR);
    hipLaunchKernelGGL(phaseLH, dim3(BB*S), dim3(512), 0, stream,
                       pred, inst, derived, part, part2, S);
    hipLaunchKernelGGL(phaseM, dim3(960), dim3(256), 0, stream, part, part_m, S);
    hipLaunchKernelGGL(phaseLS, dim3(NSEG), dim3(256), 0, stream,
                       part_m, part2, stats, results, S);
    hipLaunchKernelGGL(phase5, dim3(1), dim3(64), 0, stream,
                       stats, results, bgseedR, focalR, out);
}

// Round 9
// 80.641 us; speedup vs baseline: 1.1812x; 1.1812x over previous
//
#include <hip/hip_runtime.h>
#include <math.h>

#define BB 8
#define HWH (512*512)
#define NID 15
#define NSEG (BB*NID)
#define NBINS 256
#define AAF ((float)NBINS/13.0f)
#define LOG2E 1.442695041f
#define LN2 0.6931471806f

typedef unsigned int uint32;
typedef unsigned long long uint64;

__device__ __forceinline__ float ftanh(float x){
    float t = __expf(2.0f*x);
    return 1.0f - 2.0f*__builtin_amdgcn_rcpf(t + 1.0f);
}
__device__ __forceinline__ float fsigmoid(float x){
    return __builtin_amdgcn_rcpf(1.0f + __expf(-x));
}
__device__ __forceinline__ float sconst(float x){
    return __uint_as_float(__builtin_amdgcn_readfirstlane(__float_as_uint(x)));
}

// ---- phase1f: per-chunk id-stats (packed u64 + sigma + sigma^2) + focal/bgseed ----
__global__ __launch_bounds__(256, 8) void phase1f(const float* __restrict__ pred,
        const int* __restrict__ labels, const int* __restrict__ inst,
        uint64* __restrict__ pstat64, float* __restrict__ pstatf,
        float* __restrict__ pstatf2,
        float* __restrict__ bgseed_p, float* __restrict__ focal_p){
    int blk = blockIdx.x;            // 2048 blocks, 256 per image
    int b = blk >> 8;
    int t = threadIdx.x;
    int q = (blk & 255)*256 + t;     // float4 index in image

    __shared__ uint64 s64[NID];
    __shared__ float ssig[NID], ssig2[NID];
    __shared__ float wfb[4][2];
    if (t < NID){ s64[t] = 0ull; ssig[t] = 0.0f; ssig2[t] = 0.0f; }
    __syncthreads();

    const int Q = HWH/4;
    const float4* P = (const float4*)(pred + (size_t)b*6*HWH);
    const int4* L = (const int4*)(labels + (size_t)b*3*HWH);
    const int4* I = (const int4*)(inst + (size_t)b*HWH);
    float4 sg4 = P[2*Q+q], z3 = P[3*Q+q], z4 = P[4*Q+q], z5 = P[5*Q+q];
    int4 id4 = I[q];
    int4 l0 = L[q], l1 = L[Q+q], l2 = L[2*Q+q];
    int p = q*4;
    int w0 = p & 511, h0 = p >> 9;

    float facc = 0.0f, bacc = 0.0f;
    auto px = [&](float sgv, float z3v, float z4v, float z5v, int id,
                  int L0, int L1, int L2, int wv){
        float seed = fsigmoid(z5v);
        if (L2 == 0) bacc += seed*seed;
        int tc = 0, best = L0;
        if (L1 > best){ tc = 1; best = L1; }
        if (L2 > best){ tc = 2; }
        float m = fmaxf(z3v, fmaxf(z4v, z5v));
        float e3 = __expf(z3v-m), e4 = __expf(z4v-m), e5 = __expf(z5v-m);
        float sum = e3+e4+e5;
        float lse = m + __logf(sum);
        float zt = (tc==0) ? z3v : ((tc==1) ? z4v : z5v);
        float et = (tc==0) ? e3  : ((tc==1) ? e4  : e5);
        float lp = zt - lse;
        float pt = et*__builtin_amdgcn_rcpf(sum);
        float om = 1.0f - pt;
        facc -= om*om*lp;
        if (id > 0){
            atomicAdd(&s64[id-1],
                      (1ull<<42) | ((uint64)(uint32)wv<<21) | (uint64)(uint32)h0);
            atomicAdd(&ssig[id-1], sgv);
            atomicAdd(&ssig2[id-1], sgv*sgv);
        }
    };
    px(sg4.x, z3.x, z4.x, z5.x, id4.x, l0.x, l1.x, l2.x, w0);
    px(sg4.y, z3.y, z4.y, z5.y, id4.y, l0.y, l1.y, l2.y, w0+1);
    px(sg4.z, z3.z, z4.z, z5.z, id4.z, l0.z, l1.z, l2.z, w0+2);
    px(sg4.w, z3.w, z4.w, z5.w, id4.w, l0.w, l1.w, l2.w, w0+3);

    for (int o = 32; o; o >>= 1){
        facc += __shfl_xor(facc, o);
        bacc += __shfl_xor(bacc, o);
    }
    if ((t & 63) == 0){ wfb[t>>6][0] = facc; wfb[t>>6][1] = bacc; }
    __syncthreads();
    if (t < NID){
        pstat64[blk*16 + t] = s64[t];
        pstatf [blk*16 + t] = ssig[t];
        pstatf2[blk*16 + t] = ssig2[t];
    }
    if (t == 0){
        focal_p[blk]  = wfb[0][0]+wfb[1][0]+wfb[2][0]+wfb[3][0];
        bgseed_p[blk] = wfb[0][1]+wfb[1][1]+wfb[2][1]+wfb[3][1];
    }
}

// ---- phaseR: reduce partials -> stats(cnt), derived, var_sum, focalR, bgseedR ----
__global__ __launch_bounds__(512) void phaseR(const uint64* __restrict__ pstat64,
        const float* __restrict__ pstatf, const float* __restrict__ pstatf2,
        const float* __restrict__ focal_p, const float* __restrict__ bgseed_p,
        float* __restrict__ stats, float* __restrict__ derived,
        float* __restrict__ results,
        float* __restrict__ focalR, float* __restrict__ bgseedR){
    int b = blockIdx.x;              // 8 blocks
    int t = threadIdx.x;
    int k = t & 15, chunk = t >> 4;  // 32 chunks x 8 partial-blocks
    float acnt = 0, asw = 0, ash = 0, af = 0, af2 = 0;
    for (int i = 0; i < 8; i++){
        int blk = b*256 + chunk*8 + i;
        uint64 v = pstat64[blk*16 + k];
        acnt += (float)(uint32)(v >> 42);
        asw  += (float)(uint32)((v >> 21) & 0x1FFFFF);
        ash  += (float)(uint32)(v & 0x1FFFFF);
        af   += pstatf[blk*16 + k];
        af2  += pstatf2[blk*16 + k];
    }
    __shared__ float tc[16], tw[16], th[16], ts[16], ts2[16];
    if (t < 16){ tc[t]=0; tw[t]=0; th[t]=0; ts[t]=0; ts2[t]=0; }
    __syncthreads();
    atomicAdd(&tc[k], acnt);
    atomicAdd(&tw[k], asw);
    atomicAdd(&th[k], ash);
    atomicAdd(&ts[k], af);
    atomicAdd(&ts2[k], af2);
    __syncthreads();
    if (t < NID){
        float cnt = tc[t];
        float safe = fmaxf(cnt, 1.0f);
        float inv = 1.0f/safe;
        const float SC = 2.0f/511.0f;
        derived[(b*NID+t)*4+0] = tw[t]*SC*inv;
        derived[(b*NID+t)*4+1] = th[t]*SC*inv;
        float sm = ts[t]*inv;
        derived[(b*NID+t)*4+2] = __expf(10.0f*sm);
        derived[(b*NID+t)*4+3] = sm;
        stats[b*60 + t*4] = cnt;
        results[(size_t)(b*NID+t)*3 + 1] = ts2[t] - cnt*sm*sm;
    }
    int w = t >> 6, lane = t & 63;
    if (w == 0){
        float f = 0;
        for (int j = 0; j < 4; j++) f += focal_p[b*256 + j*64 + lane];
        for (int o = 32; o; o >>= 1) f += __shfl_xor(f, o);
        if (lane == 0) focalR[b] = f;
    } else if (w == 1){
        float g = 0;
        for (int j = 0; j < 4; j++) g += bgseed_p[b*256 + j*64 + lane];
        for (int o = 32; o; o >>= 1) g += __shfl_xor(g, o);
        if (lane == 0) bgseedR[b] = g;
    }
}

// ---- phaseLH: SGPR constants, ballot-aggregated bin-0, skip-own ----
__global__ __launch_bounds__(512, 8) void phaseLH(const float* __restrict__ pred,
        const int* __restrict__ inst, const float* __restrict__ derived,
        uint32* __restrict__ part, float* __restrict__ part2, int S){
    int idx = blockIdx.x;
    int b = idx & 7;                 // XCD affinity
    int sp = idx >> 3;
    int t = threadIdx.x;
    int lane = t & 63;

    __shared__ __align__(16) uint32 hist[NID*NBINS];   // (count<<16)|fg, 15 KB
    __shared__ float ssl[NID];
    __shared__ float vsB[NID];
    {
        uint4* hz = (uint4*)hist;
        for (int i = t; i < NID*NBINS/4; i += 512) hz[i] = make_uint4(0,0,0,0);
    }
    if (t < NID){
        ssl[t] = derived[(size_t)(b*NID + t)*4 + 2];
        vsB[t] = 0.0f;
    }
    // per-k constants -> SGPRs (uniform loads, readfirstlane forces scalar class)
    float kcx[NID], kcy[NID], kcs[NID];
    #pragma unroll
    for (int j = 0; j < NID; j++){
        const float* d0 = derived + (size_t)(b*NID + j)*4;
        kcx[j] = sconst(d0[0]);
        kcy[j] = sconst(d0[1]);
        kcs[j] = sconst(LOG2E*AAF*d0[2]);
    }
    __syncthreads();

    const int Q = HWH/4;
    int qps = Q / S;
    int q0 = sp * qps;
    const float* pb = pred + (size_t)b*6*HWH;
    const float4* P0 = (const float4*)pb;
    const float4* P1 = P0 + Q;
    const float* z5p = pb + 5*HWH;
    const int4* I = (const int4*)(inst + (size_t)b*HWH);
    const float SC = 2.0f/511.0f;

    for (int q = q0 + t; q < q0 + qps; q += 512){
        int4 id4 = I[q];
        float4 a = P0[q], c = P1[q];
        int p = q*4;
        float gx = (float)(p & 511)*SC;
        float gy = (float)(p >> 9)*SC;
        auto px = [&](float av, float cv, int id, float gxv, int pi){
            float ex = ftanh(av) + gxv;
            float ey = ftanh(cv) + gy;
            int own = id - 1;
            float r2own = 0.0f;
            #pragma unroll
            for (int j = 0; j < NID; j++){
                float dx = ex - kcx[j], dy = ey - kcy[j];
                float r2 = fmaf(dx, dx, dy*dy);
                if (j == own) r2own = r2;            // cndmask, no branch
                float binf = fmaf(-kcs[j], r2, (float)NBINS);
                binf = fminf(fmaxf(binf, 0.0f), (float)(NBINS-1));
                int bin = (int)binf;
                bool isown = (j == own);
                bool hot = (bin == 0) && !isown;
                uint64 bal = __ballot(hot);
                if (hot){
                    if ((bal & ((1ull << lane) - 1ull)) == 0ull)   // first hot lane
                        atomicAdd(&hist[j*NBINS],
                                  ((uint32)__popcll(bal)) << 16);
                } else if (!isown){
                    atomicAdd(&hist[j*NBINS + bin], 65536u);
                }
            }
            if (own >= 0){
                float d = __expf(-ssl[own]*r2own);
                float e = fmaf(-2.0f, d, 2.0f);
                float bf = fmaf(__log2f(e), AAF, (float)NBINS - AAF);
                bf = fminf(fmaxf(bf, 0.0f), (float)(NBINS-1));
                atomicAdd(&hist[own*NBINS + (int)bf], 65537u);      // fg entry
                float seed = fsigmoid(z5p[pi]);
                float sd = seed - d;
                atomicAdd(&vsB[own], sd*sd);
            }
        };
        px(a.x, c.x, id4.x, gx,      p);
        px(a.y, c.y, id4.y, gx+SC,   p+1);
        px(a.z, c.z, id4.z, gx+2*SC, p+2);
        px(a.w, c.w, id4.w, gx+3*SC, p+3);
    }
    __syncthreads();
    uint4* dst = (uint4*)(part + (size_t)(b*S + sp)*NID*NBINS);
    const uint4* hs = (const uint4*)hist;
    for (int i = t; i < NID*NBINS/4; i += 512) dst[i] = hs[i];
    if (t < NID) part2[(size_t)(b*S + sp)*NID + t] = vsB[t];
}

// ---- phaseM: merge S/8 slices -> 8 group-histograms per segment ----
__global__ __launch_bounds__(256) void phaseM(const uint32* __restrict__ part,
        uint32* __restrict__ part_m, int S){
    int idx = blockIdx.x;            // 960 = 8 img x 15 id x 8 groups
    int b = idx & 7;
    int r = idx >> 3;                // 0..119
    int k = r % NID;
    int g = r / NID;                 // 0..7
    int t = threadIdx.x;             // = bin
    int spn = S >> 3;
    uint32 acc = 0;
    for (int i = 0; i < spn; i++){
        const uint32* src = part + ((size_t)(b*S + g*spn + i)*NID + k)*NBINS;
        acc += src[t];
    }
    part_m[((size_t)(b*8 + g)*NID + k)*NBINS + t] = acc;
}

// ---- phaseLS: merge 8 groups + descending Lovasz scan ----
__global__ __launch_bounds__(256) void phaseLS(const uint32* __restrict__ part_m,
        const float* __restrict__ part2, const float* __restrict__ stats,
        float* __restrict__ results, int S){
    int idx = blockIdx.x;            // 120
    int b = idx & 7, k = idx >> 3;
    int seg = b*NID + k;
    int t = threadIdx.x;             // 256

    __shared__ uint32 hc[NBINS], hg[NBINS];
    __shared__ uint32 wbc[4], wbg[4], wexc[4], wexg[4];
    __shared__ float wsum[4];

    uint32 c = 0, g = 0;
    for (int gi = 0; gi < 8; gi++){
        uint32 v = part_m[((size_t)(b*8 + gi)*NID + k)*NBINS + t];
        c += v >> 16; g += v & 0xFFFFu;
    }
    hc[t] = c; hg[t] = g;
    __syncthreads();

    uint32 cd = hc[NBINS-1-t], gd = hg[NBINS-1-t];
    uint32 ci = cd, gi2 = gd;
    int lane = t & 63, w = t >> 6;
    for (int o = 1; o < 64; o <<= 1){
        uint32 cu = __shfl_up(ci, o);
        uint32 gu = __shfl_up(gi2, o);
        if (lane >= o){ ci += cu; gi2 += gu; }
    }
    if (lane == 63){ wbc[w] = ci; wbg[w] = gi2; }
    __syncthreads();
    if (t == 0){
        uint32 rc = 0, rg = 0;
        for (int i = 0; i < 4; i++){
            uint32 a = wbc[i], bq = wbg[i];
            wexc[i] = rc; wexg[i] = rg;
            rc += a; rg += bq;
        }
    }
    __syncthreads();

    float G = stats[b*60 + k*4];
    float contrib = 0.0f;
    if (G > 0.0f && (cd | gd)){
        uint32 nb = wexc[w] + (ci - cd);
        uint32 gb = wexg[w] + (gi2 - gd);
        float jp = 0.0f;
        if (nb > 0) jp = 1.0f - (G - (float)gb)/(G + (float)(nb - gb));
        uint32 n = nb + cd, gg = gb + gd;
        float j2 = 1.0f - (G - (float)gg)/(G + (float)(n - gg));
        int bin = NBINS-1-t;
        float ev = __expf(LN2*(((float)bin + 0.5f)*(13.0f/(float)NBINS) - 12.0f));
        contrib = ev*(j2 - jp);
    }
    for (int o = 32; o; o >>= 1) contrib += __shfl_xor(contrib, o);
    if ((t & 63) == 0) wsum[w] = contrib;
    __syncthreads();
    if (t == 0)
        results[(size_t)seg*3 + 0] = wsum[0]+wsum[1]+wsum[2]+wsum[3];
    if (w == 1){
        float ss = 0.0f;
        for (int sp = lane; sp < S; sp += 64)
            ss += part2[(size_t)(b*S + sp)*NID + k];
        for (int o = 32; o; o >>= 1) ss += __shfl_xor(ss, o);
        if (lane == 0) results[(size_t)seg*3 + 2] = ss;
    }
}

// ---------------- phase5: final combine ----------------
__global__ void phase5(const float* __restrict__ stats, const float* __restrict__ results,
                       const float* __restrict__ bgseedR, const float* __restrict__ focalR,
                       float* __restrict__ out){
    int t = threadIdx.x;
    __shared__ float per_b[BB];
    if (t < BB){
        float nvalid = 0.0f, lsum = 0.0f, vsum = 0.0f, ssum = 0.0f;
        for (int k = 0; k < NID; k++){
            int seg = t*NID + k;
            float cnt = stats[t*60 + k*4];
            if (cnt > 0.0f){
                nvalid += 1.0f;
                lsum += results[seg*3+0];
                vsum += results[seg*3+1]/cnt;
                ssum += results[seg*3+2];
            }
        }
        float nobj = fmaxf(nvalid, 1.0f);
        per_b[t] = lsum/nobj + 10.0f*(vsum/nobj) + (bgseedR[t] + ssum)/(float)HWH;
    }
    __syncthreads();
    if (t == 0){
        float s = 0.0f, fs = 0.0f;
        for (int b = 0; b < BB; b++){ s += per_b[b]; fs += focalR[b]; }
        out[0] = s/(float)BB + fs/(float)(BB*HWH);
    }
}

extern "C" void kernel_launch(void* const* d_in, const int* in_sizes, int n_in,
                              void* d_out, int out_size, void* d_ws, size_t ws_size,
                              hipStream_t stream){
    const float* pred  = (const float*)d_in[0];
    const int*   labels= (const int*)d_in[1];
    const int*   inst  = (const int*)d_in[2];
    float* out = (float*)d_out;

    auto need = [](int S){
        return (size_t)BB*S*NID*NBINS*4ull       // hist slabs
             + (size_t)120*8*NBINS*4ull          // group merge slabs
             + (size_t)BB*S*NID*4ull             // seed partials
             + 2048ull*16*8 + 2048ull*16*4*2     // pstat64 + pstatf + pstatf2
             + 2048ull*4*2                       // focal_p, bgseed_p
             + (480+480+360+16)*4ull;
    };
    int S = 16;
    if      (ws_size >= need(128)) S = 128;
    else if (ws_size >= need(64))  S = 64;
    else if (ws_size >= need(32))  S = 32;

    uint32* part   = (uint32*)d_ws;
    uint32* part_m = part + (size_t)BB*S*NID*NBINS;
    float* part2   = (float*)(part_m + (size_t)120*8*NBINS);
    uint64* pstat64= (uint64*)(part2 + (size_t)BB*S*NID);
    float* pstatf  = (float*)(pstat64 + 2048*16);
    float* pstatf2 = pstatf + 2048*16;
    float* focal_p = pstatf2 + 2048*16;
    float* bgseed_p= focal_p + 2048;
    float* stats   = bgseed_p + 2048;
    float* derived = stats + 480;
    float* results = derived + 480;
    float* focalR  = results + 360;
    float* bgseedR = focalR + 8;

    hipLaunchKernelGGL(phase1f, dim3(2048), dim3(256), 0, stream,
                       pred, labels, inst, pstat64, pstatf, pstatf2, bgseed_p, focal_p);
    hipLaunchKernelGGL(phaseR, dim3(8), dim3(512), 0, stream,
                       pstat64, pstatf, pstatf2, focal_p, bgseed_p,
                       stats, derived, results, focalR, bgseedR);
    hipLaunchKernelGGL(phaseLH, dim3(BB*S), dim3(512), 0, stream,
                       pred, inst, derived, part, part2, S);
    hipLaunchKernelGGL(phaseM, dim3(960), dim3(256), 0, stream, part, part_m, S);
    hipLaunchKernelGGL(phaseLS, dim3(NSEG), dim3(256), 0, stream,
                       part_m, part2, stats, results, S);
    hipLaunchKernelGGL(phase5, dim3(1), dim3(64), 0, stream,
                       stats, results, bgseedR, focalR, out);
}

// Round 10
// 78.465 us; speedup vs baseline: 1.2140x; 1.0277x over previous
//
#include <hip/hip_runtime.h>
#include <math.h>

#define BB 8
#define HWH (512*512)
#define NID 15
#define NSEG (BB*NID)
#define NBINS 256
#define AAF ((float)NBINS/13.0f)
#define LOG2E 1.442695041f
#define LN2 0.6931471806f
#define SLICES 128

typedef unsigned int uint32;
typedef unsigned long long uint64;

__device__ __forceinline__ float ftanh(float x){
    float t = __expf(2.0f*x);
    return 1.0f - 2.0f*__builtin_amdgcn_rcpf(t + 1.0f);
}
__device__ __forceinline__ float fsigmoid(float x){
    return __builtin_amdgcn_rcpf(1.0f + __expf(-x));
}
__device__ __forceinline__ float sconst(float x){
    return __uint_as_float(__builtin_amdgcn_readfirstlane(__float_as_uint(x)));
}

// ---- phase1f: per-chunk id-stats (packed u64 + sigma + sigma^2) + focal/bgseed ----
__global__ __launch_bounds__(256, 8) void phase1f(const float* __restrict__ pred,
        const int* __restrict__ labels, const int* __restrict__ inst,
        uint64* __restrict__ pstat64, float* __restrict__ pstatf,
        float* __restrict__ pstatf2,
        float* __restrict__ bgseed_p, float* __restrict__ focal_p){
    int blk = blockIdx.x;            // 2048 blocks, 256 per image
    int b = blk >> 8;
    int t = threadIdx.x;
    int q = (blk & 255)*256 + t;     // float4 index in image

    __shared__ uint64 s64[NID];
    __shared__ float ssig[NID], ssig2[NID];
    __shared__ float wfb[4][2];
    if (t < NID){ s64[t] = 0ull; ssig[t] = 0.0f; ssig2[t] = 0.0f; }
    __syncthreads();

    const int Q = HWH/4;
    const float4* P = (const float4*)(pred + (size_t)b*6*HWH);
    const int4* L = (const int4*)(labels + (size_t)b*3*HWH);
    const int4* I = (const int4*)(inst + (size_t)b*HWH);
    float4 sg4 = P[2*Q+q], z3 = P[3*Q+q], z4 = P[4*Q+q], z5 = P[5*Q+q];
    int4 id4 = I[q];
    int4 l0 = L[q], l1 = L[Q+q], l2 = L[2*Q+q];
    int p = q*4;
    int w0 = p & 511, h0 = p >> 9;

    float facc = 0.0f, bacc = 0.0f;
    auto px = [&](float sgv, float z3v, float z4v, float z5v, int id,
                  int L0, int L1, int L2, int wv){
        float seed = fsigmoid(z5v);
        if (L2 == 0) bacc += seed*seed;
        int tc = 0, best = L0;
        if (L1 > best){ tc = 1; best = L1; }
        if (L2 > best){ tc = 2; }
        float m = fmaxf(z3v, fmaxf(z4v, z5v));
        float e3 = __expf(z3v-m), e4 = __expf(z4v-m), e5 = __expf(z5v-m);
        float sum = e3+e4+e5;
        float lse = m + __logf(sum);
        float zt = (tc==0) ? z3v : ((tc==1) ? z4v : z5v);
        float et = (tc==0) ? e3  : ((tc==1) ? e4  : e5);
        float lp = zt - lse;
        float pt = et*__builtin_amdgcn_rcpf(sum);
        float om = 1.0f - pt;
        facc -= om*om*lp;
        if (id > 0){
            atomicAdd(&s64[id-1],
                      (1ull<<42) | ((uint64)(uint32)wv<<21) | (uint64)(uint32)h0);
            atomicAdd(&ssig[id-1], sgv);
            atomicAdd(&ssig2[id-1], sgv*sgv);
        }
    };
    px(sg4.x, z3.x, z4.x, z5.x, id4.x, l0.x, l1.x, l2.x, w0);
    px(sg4.y, z3.y, z4.y, z5.y, id4.y, l0.y, l1.y, l2.y, w0+1);
    px(sg4.z, z3.z, z4.z, z5.z, id4.z, l0.z, l1.z, l2.z, w0+2);
    px(sg4.w, z3.w, z4.w, z5.w, id4.w, l0.w, l1.w, l2.w, w0+3);

    for (int o = 32; o; o >>= 1){
        facc += __shfl_xor(facc, o);
        bacc += __shfl_xor(bacc, o);
    }
    if ((t & 63) == 0){ wfb[t>>6][0] = facc; wfb[t>>6][1] = bacc; }
    __syncthreads();
    if (t < NID){
        pstat64[blk*16 + t] = s64[t];
        pstatf [blk*16 + t] = ssig[t];
        pstatf2[blk*16 + t] = ssig2[t];
    }
    if (t == 0){
        focal_p[blk]  = wfb[0][0]+wfb[1][0]+wfb[2][0]+wfb[3][0];
        bgseed_p[blk] = wfb[0][1]+wfb[1][1]+wfb[2][1]+wfb[3][1];
    }
}

// ---- phaseR: reduce partials -> stats, derived, var_sum; zero final hist ----
__global__ __launch_bounds__(512) void phaseR(const uint64* __restrict__ pstat64,
        const float* __restrict__ pstatf, const float* __restrict__ pstatf2,
        const float* __restrict__ focal_p, const float* __restrict__ bgseed_p,
        float* __restrict__ stats, float* __restrict__ derived,
        float* __restrict__ results,
        float* __restrict__ focalR, float* __restrict__ bgseedR,
        uint32* __restrict__ Hzero, float* __restrict__ part2f){
    int b = blockIdx.x;              // 8 blocks
    int t = threadIdx.x;

    // zero final histograms (Hc+Hg = 2*NSEG*NBINS u32) and seed partials
    {
        const int stripe = 2*NSEG*NBINS/8;      // 7680 per block
        for (int i = b*stripe + t; i < (b+1)*stripe; i += 512) Hzero[i] = 0u;
        if (b == 0 && t < NSEG) part2f[t] = 0.0f;
    }

    int k = t & 15, chunk = t >> 4;  // 32 chunks x 8 partial-blocks
    float acnt = 0, asw = 0, ash = 0, af = 0, af2 = 0;
    for (int i = 0; i < 8; i++){
        int blk = b*256 + chunk*8 + i;
        uint64 v = pstat64[blk*16 + k];
        acnt += (float)(uint32)(v >> 42);
        asw  += (float)(uint32)((v >> 21) & 0x1FFFFF);
        ash  += (float)(uint32)(v & 0x1FFFFF);
        af   += pstatf[blk*16 + k];
        af2  += pstatf2[blk*16 + k];
    }
    __shared__ float tc[16], tw[16], th[16], ts[16], ts2[16];
    if (t < 16){ tc[t]=0; tw[t]=0; th[t]=0; ts[t]=0; ts2[t]=0; }
    __syncthreads();
    atomicAdd(&tc[k], acnt);
    atomicAdd(&tw[k], asw);
    atomicAdd(&th[k], ash);
    atomicAdd(&ts[k], af);
    atomicAdd(&ts2[k], af2);
    __syncthreads();
    if (t < NID){
        float cnt = tc[t];
        float safe = fmaxf(cnt, 1.0f);
        float inv = 1.0f/safe;
        const float SC = 2.0f/511.0f;
        derived[(b*NID+t)*4+0] = tw[t]*SC*inv;
        derived[(b*NID+t)*4+1] = th[t]*SC*inv;
        float sm = ts[t]*inv;
        derived[(b*NID+t)*4+2] = __expf(10.0f*sm);
        derived[(b*NID+t)*4+3] = sm;
        stats[b*60 + t*4] = cnt;
        results[(size_t)(b*NID+t)*3 + 1] = ts2[t] - cnt*sm*sm;
    }
    int w = t >> 6, lane = t & 63;
    if (w == 0){
        float f = 0;
        for (int j = 0; j < 4; j++) f += focal_p[b*256 + j*64 + lane];
        for (int o = 32; o; o >>= 1) f += __shfl_xor(f, o);
        if (lane == 0) focalR[b] = f;
    } else if (w == 1){
        float g = 0;
        for (int j = 0; j < 4; j++) g += bgseed_p[b*256 + j*64 + lane];
        for (int o = 32; o; o >>= 1) g += __shfl_xor(g, o);
        if (lane == 0) bgseedR[b] = g;
    }
}

// ---- phaseLH: LDS hist per slice; sparse atomic accumulate into final hist ----
__global__ __launch_bounds__(512, 8) void phaseLH(const float* __restrict__ pred,
        const int* __restrict__ inst, const float* __restrict__ derived,
        uint32* __restrict__ Hc, uint32* __restrict__ Hg,
        float* __restrict__ part2f){
    int idx = blockIdx.x;
    int b = idx & 7;                 // XCD affinity
    int sp = idx >> 3;
    int t = threadIdx.x;
    int lane = t & 63;

    __shared__ __align__(16) uint32 hist[NID*NBINS];   // (count<<16)|fg, 15 KB
    __shared__ float ssl[NID];
    __shared__ float vsB[NID];
    {
        uint4* hz = (uint4*)hist;
        for (int i = t; i < NID*NBINS/4; i += 512) hz[i] = make_uint4(0,0,0,0);
    }
    if (t < NID){
        ssl[t] = derived[(size_t)(b*NID + t)*4 + 2];
        vsB[t] = 0.0f;
    }
    float kcx[NID], kcy[NID], kcs[NID];
    #pragma unroll
    for (int j = 0; j < NID; j++){
        const float* d0 = derived + (size_t)(b*NID + j)*4;
        kcx[j] = sconst(d0[0]);
        kcy[j] = sconst(d0[1]);
        kcs[j] = sconst(LOG2E*AAF*d0[2]);
    }
    __syncthreads();

    const int Q = HWH/4;
    const int qps = Q / SLICES;      // 512
    int q0 = sp * qps;
    const float* pb = pred + (size_t)b*6*HWH;
    const float4* P0 = (const float4*)pb;
    const float4* P1 = P0 + Q;
    const float* z5p = pb + 5*HWH;
    const int4* I = (const int4*)(inst + (size_t)b*HWH);
    const float SC = 2.0f/511.0f;

    for (int q = q0 + t; q < q0 + qps; q += 512){
        int4 id4 = I[q];
        float4 a = P0[q], c = P1[q];
        int p = q*4;
        float gx = (float)(p & 511)*SC;
        float gy = (float)(p >> 9)*SC;
        auto px = [&](float av, float cv, int id, float gxv, int pi){
            float ex = ftanh(av) + gxv;
            float ey = ftanh(cv) + gy;
            int own = id - 1;
            float r2own = 0.0f;
            #pragma unroll
            for (int j = 0; j < NID; j++){
                float dx = ex - kcx[j], dy = ey - kcy[j];
                float r2 = fmaf(dx, dx, dy*dy);
                if (j == own) r2own = r2;            // cndmask, no branch
                float binf = fmaf(-kcs[j], r2, (float)NBINS);
                binf = fminf(fmaxf(binf, 0.0f), (float)(NBINS-1));
                int bin = (int)binf;
                bool isown = (j == own);
                bool hot = (bin == 0) && !isown;
                uint64 bal = __ballot(hot);
                if (hot){
                    if ((bal & ((1ull << lane) - 1ull)) == 0ull)   // first hot lane
                        atomicAdd(&hist[j*NBINS],
                                  ((uint32)__popcll(bal)) << 16);
                } else if (!isown){
                    atomicAdd(&hist[j*NBINS + bin], 65536u);
                }
            }
            if (own >= 0){
                float d = __expf(-ssl[own]*r2own);
                float e = fmaf(-2.0f, d, 2.0f);
                float bf = fmaf(__log2f(e), AAF, (float)NBINS - AAF);
                bf = fminf(fmaxf(bf, 0.0f), (float)(NBINS-1));
                atomicAdd(&hist[own*NBINS + (int)bf], 65537u);      // fg entry
                float seed = fsigmoid(z5p[pi]);
                float sd = seed - d;
                atomicAdd(&vsB[own], sd*sd);
            }
        };
        px(a.x, c.x, id4.x, gx,      p);
        px(a.y, c.y, id4.y, gx+SC,   p+1);
        px(a.z, c.z, id4.z, gx+2*SC, p+2);
        px(a.w, c.w, id4.w, gx+3*SC, p+3);
    }
    __syncthreads();
    // sparse atomic accumulation into the final per-segment histograms (L2-resident)
    size_t base = (size_t)b*NID*NBINS;
    for (int i = t; i < NID*NBINS; i += 512){
        uint32 v = hist[i];
        if (v){
            uint32 cc = v >> 16, gg = v & 0xFFFFu;
            if (cc) atomicAdd(&Hc[base + i], cc);
            if (gg) atomicAdd(&Hg[base + i], gg);
        }
    }
    if (t < NID && vsB[t] != 0.0f)
        atomicAdd(&part2f[b*NID + t], vsB[t]);
}

// ---- phaseLS: descending Lovasz scan directly on final hist ----
__global__ __launch_bounds__(256) void phaseLS(const uint32* __restrict__ Hc,
        const uint32* __restrict__ Hg, const float* __restrict__ part2f,
        const float* __restrict__ stats, float* __restrict__ results){
    int idx = blockIdx.x;            // 120
    int b = idx & 7, k = idx >> 3;
    int seg = b*NID + k;
    int t = threadIdx.x;             // 256

    __shared__ uint32 wbc[4], wbg[4], wexc[4], wexg[4];
    __shared__ float wsum[4];

    size_t base = (size_t)seg*NBINS;
    uint32 cd = Hc[base + NBINS-1-t];       // thread t handles bin NBINS-1-t
    uint32 gd = Hg[base + NBINS-1-t];
    uint32 ci = cd, gi2 = gd;
    int lane = t & 63, w = t >> 6;
    for (int o = 1; o < 64; o <<= 1){
        uint32 cu = __shfl_up(ci, o);
        uint32 gu = __shfl_up(gi2, o);
        if (lane >= o){ ci += cu; gi2 += gu; }
    }
    if (lane == 63){ wbc[w] = ci; wbg[w] = gi2; }
    __syncthreads();
    if (t == 0){
        uint32 rc = 0, rg = 0;
        for (int i = 0; i < 4; i++){
            uint32 a = wbc[i], bq = wbg[i];
            wexc[i] = rc; wexg[i] = rg;
            rc += a; rg += bq;
        }
    }
    __syncthreads();

    float G = stats[b*60 + k*4];
    float contrib = 0.0f;
    if (G > 0.0f && (cd | gd)){
        uint32 nb = wexc[w] + (ci - cd);
        uint32 gb = wexg[w] + (gi2 - gd);
        float jp = 0.0f;
        if (nb > 0) jp = 1.0f - (G - (float)gb)/(G + (float)(nb - gb));
        uint32 n = nb + cd, gg = gb + gd;
        float j2 = 1.0f - (G - (float)gg)/(G + (float)(n - gg));
        int bin = NBINS-1-t;
        float ev = __expf(LN2*(((float)bin + 0.5f)*(13.0f/(float)NBINS) - 12.0f));
        contrib = ev*(j2 - jp);
    }
    for (int o = 32; o; o >>= 1) contrib += __shfl_xor(contrib, o);
    if ((t & 63) == 0) wsum[w] = contrib;
    __syncthreads();
    if (t == 0){
        results[(size_t)seg*3 + 0] = wsum[0]+wsum[1]+wsum[2]+wsum[3];
        results[(size_t)seg*3 + 2] = part2f[seg];
    }
}

// ---------------- phase5: final combine ----------------
__global__ void phase5(const float* __restrict__ stats, const float* __restrict__ results,
                       const float* __restrict__ bgseedR, const float* __restrict__ focalR,
                       float* __restrict__ out){
    int t = threadIdx.x;
    __shared__ float per_b[BB];
    if (t < BB){
        float nvalid = 0.0f, lsum = 0.0f, vsum = 0.0f, ssum = 0.0f;
        for (int k = 0; k < NID; k++){
            int seg = t*NID + k;
            float cnt = stats[t*60 + k*4];
            if (cnt > 0.0f){
                nvalid += 1.0f;
                lsum += results[seg*3+0];
                vsum += results[seg*3+1]/cnt;
                ssum += results[seg*3+2];
            }
        }
        float nobj = fmaxf(nvalid, 1.0f);
        per_b[t] = lsum/nobj + 10.0f*(vsum/nobj) + (bgseedR[t] + ssum)/(float)HWH;
    }
    __syncthreads();
    if (t == 0){
        float s = 0.0f, fs = 0.0f;
        for (int b = 0; b < BB; b++){ s += per_b[b]; fs += focalR[b]; }
        out[0] = s/(float)BB + fs/(float)(BB*HWH);
    }
}

extern "C" void kernel_launch(void* const* d_in, const int* in_sizes, int n_in,
                              void* d_out, int out_size, void* d_ws, size_t ws_size,
                              hipStream_t stream){
    const float* pred  = (const float*)d_in[0];
    const int*   labels= (const int*)d_in[1];
    const int*   inst  = (const int*)d_in[2];
    float* out = (float*)d_out;

    uint32* Hc     = (uint32*)d_ws;                          // NSEG*NBINS
    uint32* Hg     = Hc + (size_t)NSEG*NBINS;                // NSEG*NBINS
    float* part2f  = (float*)(Hg + (size_t)NSEG*NBINS);      // NSEG
    uint64* pstat64= (uint64*)(part2f + NSEG);               // 2048*16
    float* pstatf  = (float*)(pstat64 + 2048*16);
    float* pstatf2 = pstatf + 2048*16;
    float* focal_p = pstatf2 + 2048*16;
    float* bgseed_p= focal_p + 2048;
    float* stats   = bgseed_p + 2048;
    float* derived = stats + 480;
    float* results = derived + 480;
    float* focalR  = results + 360;
    float* bgseedR = focalR + 8;

    hipLaunchKernelGGL(phase1f, dim3(2048), dim3(256), 0, stream,
                       pred, labels, inst, pstat64, pstatf, pstatf2, bgseed_p, focal_p);
    hipLaunchKernelGGL(phaseR, dim3(8), dim3(512), 0, stream,
                       pstat64, pstatf, pstatf2, focal_p, bgseed_p,
                       stats, derived, results, focalR, bgseedR, Hc, part2f);
    hipLaunchKernelGGL(phaseLH, dim3(BB*SLICES), dim3(512), 0, stream,
                       pred, inst, derived, Hc, Hg, part2f);
    hipLaunchKernelGGL(phaseLS, dim3(NSEG), dim3(256), 0, stream,
                       Hc, Hg, part2f, stats, results);
    hipLaunchKernelGGL(phase5, dim3(1), dim3(64), 0, stream,
                       stats, results, bgseedR, focalR, out);
}